// Round 4
// baseline (270.285 us; speedup 1.0000x reference)
//
#include <hip/hip_runtime.h>
#include <hip/hip_bf16.h>

typedef unsigned short ushort_t;
typedef __attribute__((ext_vector_type(8))) short short8;
typedef __attribute__((ext_vector_type(4))) float f32x4;

// Problem constants (B=8, L=1025, E=384, H=6, D=64, WIN=33, PAD=16)
constexpr int Bc = 8;
constexpr int Lc = 1025;
constexpr int Ec = 384;
constexpr int Hc = 6;
constexpr int Dc = 64;
constexpr int MT = Bc * Lc;              // 8200 rows
constexpr int BHLD = Bc * Hc * Lc * Dc;  // 3,148,800 elems per tensor
constexpr int LT = 1032;                 // padded v_t row stride (16B-aligned rows)
constexpr float SCALE = 0.125f;          // 1/sqrt(64)

__device__ __forceinline__ float bf2f(ushort_t u) {
    union { unsigned int u; float f; } v; v.u = ((unsigned int)u) << 16; return v.f;
}
__device__ __forceinline__ ushort_t f2bf(float f) {
    union { float f; unsigned int u; } v; v.f = f;
    unsigned int r = v.u + 0x7FFFu + ((v.u >> 16) & 1u);
    return (ushort_t)(r >> 16);
}

#define GLOAD_LDS16(gp, lp)                                                          \
    __builtin_amdgcn_global_load_lds(                                                \
        (const __attribute__((address_space(1))) unsigned int*)(gp),                 \
        (__attribute__((address_space(3))) unsigned int*)(lp), 16, 0, 0)

// ---------------------------------------------------------------------------
// Kernel 0: merged prep.  Blocks [0, 3075): cast x fp32->bf16 (float4 per
// thread).  Blocks [3075, 3651): transpose+cast the 4 weight matrices.
// ---------------------------------------------------------------------------
__global__ __launch_bounds__(256) void prep_kernel(
    const float* __restrict__ x, ushort_t* __restrict__ xb,
    const float* __restrict__ Wq, const float* __restrict__ Wk,
    const float* __restrict__ Wv, const float* __restrict__ Wo,
    ushort_t* __restrict__ Wt_all)
{
    const int bid = blockIdx.x;
    if (bid < 3075) {
        int i = bid * 256 + threadIdx.x;
        float4 v = ((const float4*)x)[i];
        ushort4 o;
        o.x = f2bf(v.x); o.y = f2bf(v.y); o.z = f2bf(v.z); o.w = f2bf(v.w);
        ((ushort4*)xb)[i] = o;
        return;
    }
    __shared__ float t[32][33];
    const int b2 = bid - 3075;
    const int z = b2 / 144, rem = b2 - z * 144;
    const int yy = rem / 12, xx = rem - yy * 12;
    const float* W = (z == 0) ? Wq : (z == 1) ? Wk : (z == 2) ? Wv : Wo;
    ushort_t* Wt = Wt_all + (size_t)z * Ec * Ec;
    const int x0 = xx * 32, y0 = yy * 32;
    const int tx = threadIdx.x & 31, ty = threadIdx.x >> 5;
#pragma unroll
    for (int j = 0; j < 4; j++)
        t[ty + 8 * j][tx] = W[(size_t)(y0 + ty + 8 * j) * Ec + x0 + tx];
    __syncthreads();
#pragma unroll
    for (int j = 0; j < 4; j++)
        Wt[(size_t)(x0 + ty + 8 * j) * Ec + y0 + tx] = f2bf(t[tx][ty + 8 * j]);
}

// ---------------------------------------------------------------------------
// Kernel 1: fused QKV projection via bf16 MFMA (128x128 tile, BK=64, 4 waves).
// ---------------------------------------------------------------------------
__global__ __launch_bounds__(256) void qkv_mfma_kernel(
    const ushort_t* __restrict__ xb, const ushort_t* __restrict__ Wt,
    const float* __restrict__ bq, const float* __restrict__ bk,
    const float* __restrict__ bv, ushort_t* __restrict__ qkv)
{
    __shared__ __align__(16) ushort_t As[128 * 64];
    __shared__ __align__(16) ushort_t Bs[128 * 64];

    const int tid = threadIdx.x;
    const int lane = tid & 63;
    const int wid = tid >> 6;
    const int wr = wid >> 1, wc = wid & 1;
    const int m0 = blockIdx.x * 128;
    const int n0 = blockIdx.y * 128;
    const int which = n0 / Ec;
    const int nm0 = n0 - which * Ec;
    const ushort_t* Wmat = Wt + (size_t)which * Ec * Ec;
    const float* bias = (which == 0) ? bq : (which == 1) ? bk : bv;

    f32x4 acc[4][4];
#pragma unroll
    for (int i = 0; i < 4; i++)
#pragma unroll
        for (int j = 0; j < 4; j++) acc[i][j] = (f32x4){0.f, 0.f, 0.f, 0.f};

    for (int kt = 0; kt < Ec; kt += 64) {
#pragma unroll
        for (int c = 0; c < 4; c++) {
            int ci  = (wid * 4 + c) * 64 + lane;
            int row = ci >> 3, kc = ci & 7;
            int kcs = kc ^ (row & 7);
            int rowA = m0 + row; rowA = rowA < MT ? rowA : MT - 1;
            GLOAD_LDS16(xb + (size_t)rowA * Ec + kt + kcs * 8,
                        As + (size_t)(wid * 4 + c) * 512);
            GLOAD_LDS16(Wmat + (size_t)(nm0 + row) * Ec + kt + kcs * 8,
                        Bs + (size_t)(wid * 4 + c) * 512);
        }
        __syncthreads();

#pragma unroll
        for (int ki = 0; ki < 2; ki++) {
            short8 a[4], b[4];
            const int kchunk = ki * 4 + (lane >> 4);
#pragma unroll
            for (int mi = 0; mi < 4; mi++) {
                int row = wr * 64 + mi * 16 + (lane & 15);
                a[mi] = *(const short8*)(As + row * 64 + ((kchunk ^ (row & 7)) * 8));
            }
#pragma unroll
            for (int ni = 0; ni < 4; ni++) {
                int row = wc * 64 + ni * 16 + (lane & 15);
                b[ni] = *(const short8*)(Bs + row * 64 + ((kchunk ^ (row & 7)) * 8));
            }
#pragma unroll
            for (int mi = 0; mi < 4; mi++)
#pragma unroll
                for (int ni = 0; ni < 4; ni++)
                    acc[mi][ni] = __builtin_amdgcn_mfma_f32_16x16x32_bf16(
                        a[mi], b[ni], acc[mi][ni], 0, 0, 0);
        }
        __syncthreads();
    }

    const int colL = lane & 15;
    const int rowL = (lane >> 4) * 4;
#pragma unroll
    for (int ni = 0; ni < 4; ni++) {
        int nm = nm0 + wc * 64 + ni * 16 + colL;
        float bv_ = bias[nm];
        int h = nm >> 6, d = nm & 63;
#pragma unroll
        for (int mi = 0; mi < 4; mi++) {
#pragma unroll
            for (int r = 0; r < 4; r++) {
                int m = m0 + wr * 64 + mi * 16 + rowL + r;
                if (m < MT) {
                    int b_ = m / Lc, l = m - b_ * Lc;
                    qkv[(size_t)which * BHLD +
                        ((size_t)(b_ * Hc + h) * Lc + l) * Dc + d] =
                        f2bf(acc[mi][ni][r] + bv_);
                }
            }
        }
    }
}

// ---------------------------------------------------------------------------
// Kernel 2: V transpose (B,H,L,D) -> (B,H,D,Lpad) bf16, for PV B-operand.
// ---------------------------------------------------------------------------
__global__ __launch_bounds__(256) void vT_kernel(
    const ushort_t* __restrict__ qkv, ushort_t* __restrict__ vt)
{
    __shared__ ushort_t t[64][68];
    const int bh = blockIdx.y;
    const int l0 = blockIdx.x * 64;        // gridDim.x = 17
    const ushort_t* V = qkv + 2 * (size_t)BHLD + (size_t)bh * Lc * Dc;
    ushort_t* vto = vt + (size_t)bh * 64 * LT;
    const int tid = threadIdx.x;
#pragma unroll
    for (int i = 0; i < 4; i++) {
        int idx = tid + i * 256;
        int l = idx >> 4, dc = idx & 15;
        int ls = l0 + l; ls = ls > 1024 ? 1024 : ls;
        ushort4 v = *(const ushort4*)(V + (size_t)ls * Dc + dc * 4);
        *(ushort4*)&t[l][dc * 4] = v;
    }
    __syncthreads();
#pragma unroll
    for (int i = 0; i < 4; i++) {
        int idx = tid + i * 256;
        int d = idx >> 4, lc = idx & 15;
        ushort4 o;
        o.x = t[lc * 4 + 0][d]; o.y = t[lc * 4 + 1][d];
        o.z = t[lc * 4 + 2][d]; o.w = t[lc * 4 + 3][d];
        int lw = l0 + lc * 4;
        if (lw <= 1024)
            *(ushort4*)(vto + (size_t)d * LT + lw) = o;
    }
}

// ---------------------------------------------------------------------------
// Kernel 3: attention.  grid (17, 48), 256 threads (4 waves).
//   blockIdx.x < 16 : windowed MFMA attention (64 queries, 128 key slots)
//   blockIdx.x == 16: CLS row, lane-parallel over D, full 1025-key softmax
// ---------------------------------------------------------------------------
__global__ __launch_bounds__(256) void attn_kernel(
    const ushort_t* __restrict__ qkv, const ushort_t* __restrict__ vt,
    ushort_t* __restrict__ attnb)
{
    __shared__ __align__(16) ushort_t Kb[128 * 64];
    __shared__ __align__(16) ushort_t Vb[64 * 128];
    __shared__ __align__(16) ushort_t QP[64 * 128];

    const int bh = blockIdx.y;
    const int tid = threadIdx.x, lane = tid & 63, wid = tid >> 6;
    const ushort_t* Qg = qkv + (size_t)bh * Lc * Dc;
    const ushort_t* Kg = Qg + (size_t)BHLD;
    const int b_ = bh / Hc, h = bh - b_ * Hc;

    if (blockIdx.x == 16) {
        // ================= CLS branch (lane-parallel) =================
        const ushort_t* Vg = Qg + 2 * (size_t)BHLD;
        float* sc  = (float*)Kb;     // [1025] scores -> p
        float* red = (float*)Vb;     // [0..3] max, [8..11] sum, [64..319] pv

        // Q row 0 into regs: lane&31 owns dwords (2 bf16)
        unsigned int qw = ((const unsigned int*)Qg)[lane & 31];
        float qa = bf2f((ushort_t)(qw & 0xffff)), qb = bf2f((ushort_t)(qw >> 16));

        float lmax = -1e30f;
        for (int s = 0; s < 129; ++s) {          // 8 keys/step across 4 waves
            int k = s * 8 + wid * 2 + (lane >> 5);
            bool ok = k < Lc;
            int kc = ok ? k : 0;
            unsigned int kw = ((const unsigned int*)(Kg + (size_t)kc * Dc))[lane & 31];
            float p = qa * bf2f((ushort_t)(kw & 0xffff)) +
                      qb * bf2f((ushort_t)(kw >> 16));
            p += __shfl_xor(p, 1);  p += __shfl_xor(p, 2);
            p += __shfl_xor(p, 4);  p += __shfl_xor(p, 8);
            p += __shfl_xor(p, 16);                       // 32-lane dot
            float s0 = p * SCALE;
            if (ok && (lane & 31) == 0) sc[k] = s0;
            float so = __shfl_xor(s0, 32);                // other half's key
            int ko = s * 8 + wid * 2 + 1 - (lane >> 5);
            if (!ok) s0 = -1e30f;
            if (ko >= Lc) so = -1e30f;
            lmax = fmaxf(lmax, fmaxf(s0, so));
        }
        if (lane == 0) red[wid] = lmax;
        __syncthreads();
        const float M = fmaxf(fmaxf(red[0], red[1]), fmaxf(red[2], red[3]));

        float lsum = 0.f;
        for (int k = tid; k < Lc; k += 256) {
            float p = __expf(sc[k] - M);
            sc[k] = p;
            lsum += p;
        }
        lsum += __shfl_xor(lsum, 1);  lsum += __shfl_xor(lsum, 2);
        lsum += __shfl_xor(lsum, 4);  lsum += __shfl_xor(lsum, 8);
        lsum += __shfl_xor(lsum, 16); lsum += __shfl_xor(lsum, 32);
        __syncthreads();              // sc[] writes complete before PV reads
        if (lane == 0) red[8 + wid] = lsum;
        __syncthreads();
        const float S = red[8] + red[9] + red[10] + red[11];

        // PV: lane = d, wave strides keys
        float acc = 0.f;
        for (int k = wid; k < Lc; k += 4)
            acc += sc[k] * bf2f(Vg[(size_t)k * Dc + lane]);
        red[64 + wid * 64 + lane] = acc;
        __syncthreads();
        if (tid < 64) {
            float o = red[64 + tid] + red[128 + tid] + red[192 + tid] + red[256 + tid];
            attnb[(size_t)(b_ * Lc) * Ec + h * 64 + tid] = f2bf(o / S);
        }
        return;
    }

    // ================= windowed branch =================
    const int t = blockIdx.x;
    const int l0 = 1 + t * 64, k0 = l0 - 17;
    const ushort_t* Vt = vt + (size_t)bh * 64 * LT;

#pragma unroll
    for (int i = 0; i < 4; i++) {
        int p = (i * 4 + wid) * 64 + lane;
        {   // K: row j, 8 chunks of 16B
            int j = p >> 3, c = p & 7, g = c ^ (j & 7);
            int kp = (j <= 111) ? min(max(k0 + j, 0), 1024) : 0;
            GLOAD_LDS16(Kg + (size_t)kp * Dc + g * 8,
                        Kb + (size_t)(i * 4 + wid) * 512);
        }
        {   // V^T: row d, 16 chunks of 8 kpos
            int d = p >> 4, jc = p & 15, g = jc ^ (d & 15);
            int kb = (g <= 13) ? max(k0 + g * 8, 0) : 0;
            GLOAD_LDS16(Vt + (size_t)d * LT + kb,
                        Vb + (size_t)(i * 4 + wid) * 512);
        }
    }
#pragma unroll
    for (int i = 0; i < 2; i++) {
        int p = (i * 4 + wid) * 64 + lane;
        int q = p >> 3, c = p & 7, g = c ^ (q & 7);
        GLOAD_LDS16(Qg + (size_t)(l0 + q) * Dc + g * 8,
                    QP + (size_t)(i * 4 + wid) * 512);
    }
    __syncthreads();

    f32x4 sacc[8];
#pragma unroll
    for (int tj = 0; tj < 8; tj++) sacc[tj] = (f32x4){0.f, 0.f, 0.f, 0.f};
#pragma unroll
    for (int ki = 0; ki < 2; ki++) {
        const int gc = ki * 4 + (lane >> 4);
        const int qrow = wid * 16 + (lane & 15);
        short8 a = *(const short8*)(QP + qrow * 64 + ((gc ^ (qrow & 7)) * 8));
#pragma unroll
        for (int tj = 0; tj < 8; tj++) {
            int jrow = tj * 16 + (lane & 15);
            short8 b = *(const short8*)(Kb + jrow * 64 + ((gc ^ (jrow & 7)) * 8));
            sacc[tj] = __builtin_amdgcn_mfma_f32_16x16x32_bf16(a, b, sacc[tj], 0, 0, 0);
        }
    }
    __syncthreads();   // Q region dead; P may overwrite it

    const int qb = wid * 16 + (lane >> 4) * 4;
    const int cl = lane & 15;
    float inv[4];
#pragma unroll
    for (int r = 0; r < 4; r++) {
        const int q = qb + r;
        float sv[8];
        float mx = -1e30f;
#pragma unroll
        for (int tj = 0; tj < 8; tj++) {
            int j = tj * 16 + cl;
            int kp = k0 + j;
            bool valid = (j == 112) ||
                         ((j >= q + 1) && (j <= q + 33) && (kp >= 1) && (kp <= 1024));
            float s = valid ? sacc[tj][r] * SCALE : -1e30f;
            sv[tj] = s;
            mx = fmaxf(mx, s);
        }
        mx = fmaxf(mx, __shfl_xor(mx, 1));
        mx = fmaxf(mx, __shfl_xor(mx, 2));
        mx = fmaxf(mx, __shfl_xor(mx, 4));
        mx = fmaxf(mx, __shfl_xor(mx, 8));
        float sum = 0.f;
#pragma unroll
        for (int tj = 0; tj < 8; tj++) {
            float pv = __expf(sv[tj] - mx);
            sv[tj] = pv;
            sum += pv;
        }
        sum += __shfl_xor(sum, 1);
        sum += __shfl_xor(sum, 2);
        sum += __shfl_xor(sum, 4);
        sum += __shfl_xor(sum, 8);
        inv[r] = 1.f / sum;
#pragma unroll
        for (int tj = 0; tj < 8; tj++) {
            int j = tj * 16 + cl;
            QP[q * 128 + (((j >> 3) ^ (q & 15)) * 8) + (j & 7)] = f2bf(sv[tj]);
        }
    }
    __syncthreads();

    f32x4 oacc[4];
#pragma unroll
    for (int dt = 0; dt < 4; dt++) oacc[dt] = (f32x4){0.f, 0.f, 0.f, 0.f};
#pragma unroll
    for (int kc = 0; kc < 4; kc++) {
        const int gc = kc * 4 + (lane >> 4);
        const int qrow = wid * 16 + (lane & 15);
        short8 pa = *(const short8*)(QP + qrow * 128 + ((gc ^ (qrow & 15)) * 8));
#pragma unroll
        for (int dt = 0; dt < 4; dt++) {
            int drow = dt * 16 + (lane & 15);
            short8 vb = *(const short8*)(Vb + drow * 128 + ((gc ^ (drow & 15)) * 8));
            oacc[dt] = __builtin_amdgcn_mfma_f32_16x16x32_bf16(pa, vb, oacc[dt], 0, 0, 0);
        }
    }

#pragma unroll
    for (int dt = 0; dt < 4; dt++) {
        int d = dt * 16 + cl;
#pragma unroll
        for (int r = 0; r < 4; r++) {
            int l = l0 + qb + r;
            attnb[(size_t)(b_ * Lc + l) * Ec + h * 64 + d] = f2bf(oacc[dt][r] * inv[r]);
        }
    }
}

// ---------------------------------------------------------------------------
// Kernel 4: output projection via bf16 MFMA, 64x128 tile (grid 129 x 3).
// 4 waves: wr = wid&1 (32-row half), wc = wid>>1 (64-col half); acc 2x4.
// ---------------------------------------------------------------------------
__global__ __launch_bounds__(256) void out_mfma_kernel(
    const ushort_t* __restrict__ attn_rows, const ushort_t* __restrict__ Wot,
    const float* __restrict__ bo, float* __restrict__ out)
{
    __shared__ __align__(16) ushort_t As[64 * 64];
    __shared__ __align__(16) ushort_t Bs[128 * 64];

    const int tid = threadIdx.x;
    const int lane = tid & 63;
    const int wid = tid >> 6;
    const int wr = wid & 1, wc = wid >> 1;
    const int m0 = blockIdx.x * 64;
    const int n0 = blockIdx.y * 128;

    f32x4 acc[2][4];
#pragma unroll
    for (int i = 0; i < 2; i++)
#pragma unroll
        for (int j = 0; j < 4; j++) acc[i][j] = (f32x4){0.f, 0.f, 0.f, 0.f};

    for (int kt = 0; kt < Ec; kt += 64) {
#pragma unroll
        for (int c = 0; c < 2; c++) {       // A: 64x64 = 512 chunks
            int ci  = (wid * 2 + c) * 64 + lane;
            int row = ci >> 3, kc = ci & 7;
            int kcs = kc ^ (row & 7);
            int rowA = m0 + row; rowA = rowA < MT ? rowA : MT - 1;
            GLOAD_LDS16(attn_rows + (size_t)rowA * Ec + kt + kcs * 8,
                        As + (size_t)(wid * 2 + c) * 512);
        }
#pragma unroll
        for (int c = 0; c < 4; c++) {       // B: 128x64 = 1024 chunks
            int ci  = (wid * 4 + c) * 64 + lane;
            int row = ci >> 3, kc = ci & 7;
            int kcs = kc ^ (row & 7);
            GLOAD_LDS16(Wot + (size_t)(n0 + row) * Ec + kt + kcs * 8,
                        Bs + (size_t)(wid * 4 + c) * 512);
        }
        __syncthreads();

#pragma unroll
        for (int ki = 0; ki < 2; ki++) {
            short8 a[2], b[4];
            const int kchunk = ki * 4 + (lane >> 4);
#pragma unroll
            for (int mi = 0; mi < 2; mi++) {
                int row = wr * 32 + mi * 16 + (lane & 15);
                a[mi] = *(const short8*)(As + row * 64 + ((kchunk ^ (row & 7)) * 8));
            }
#pragma unroll
            for (int ni = 0; ni < 4; ni++) {
                int row = wc * 64 + ni * 16 + (lane & 15);
                b[ni] = *(const short8*)(Bs + row * 64 + ((kchunk ^ (row & 7)) * 8));
            }
#pragma unroll
            for (int mi = 0; mi < 2; mi++)
#pragma unroll
                for (int ni = 0; ni < 4; ni++)
                    acc[mi][ni] = __builtin_amdgcn_mfma_f32_16x16x32_bf16(
                        a[mi], b[ni], acc[mi][ni], 0, 0, 0);
        }
        __syncthreads();
    }

    const int colL = lane & 15;
    const int rowL = (lane >> 4) * 4;
#pragma unroll
    for (int ni = 0; ni < 4; ni++) {
        int n = n0 + wc * 64 + ni * 16 + colL;
        float bo_v = bo[n];
#pragma unroll
        for (int mi = 0; mi < 2; mi++) {
#pragma unroll
            for (int r = 0; r < 4; r++) {
                int m = m0 + wr * 32 + mi * 16 + rowL + r;
                if (m < MT) out[(size_t)m * Ec + n] = acc[mi][ni][r] + bo_v;
            }
        }
    }
}

// ---------------------------------------------------------------------------
extern "C" void kernel_launch(void* const* d_in, const int* in_sizes, int n_in,
                              void* d_out, int out_size, void* d_ws, size_t ws_size,
                              hipStream_t stream)
{
    const float* x  = (const float*)d_in[0];
    const float* Wq = (const float*)d_in[1];
    const float* bq = (const float*)d_in[2];
    const float* Wk = (const float*)d_in[3];
    const float* bk = (const float*)d_in[4];
    const float* Wv = (const float*)d_in[5];
    const float* bv = (const float*)d_in[6];
    const float* Wo = (const float*)d_in[7];
    const float* bo = (const float*)d_in[8];
    float* out = (float*)d_out;

    // ws layout (ushort units, all 16B-aligned):
    // xb | Wt(4) | qkv(3) | v_t | attnb  ~= 32.8 MB
    ushort_t* xb    = (ushort_t*)d_ws;
    ushort_t* Wt    = xb + (size_t)MT * Ec;                  // 3,148,800
    ushort_t* qkvb  = Wt + (size_t)4 * Ec * Ec;              // + 589,824
    ushort_t* vtb   = qkvb + (size_t)3 * BHLD;               // + 9,446,400
    ushort_t* attnb = vtb + (size_t)Bc * Hc * 64 * LT;       // + 3,170,304

    prep_kernel<<<3075 + 576, 256, 0, stream>>>(x, xb, Wq, Wk, Wv, Wo, Wt);

    qkv_mfma_kernel<<<dim3((MT + 127) / 128, 9), 256, 0, stream>>>(
        xb, Wt, bq, bk, bv, qkvb);

    vT_kernel<<<dim3(17, Bc * Hc), 256, 0, stream>>>(qkvb, vtb);

    attn_kernel<<<dim3(17, Bc * Hc), 256, 0, stream>>>(qkvb, vtb, attnb);

    out_mfma_kernel<<<dim3((MT + 63) / 64, 3), 256, 0, stream>>>(
        attnb, Wt + (size_t)3 * Ec * Ec, bo, out);
}

// Round 6
// 165.219 us; speedup vs baseline: 1.6359x; 1.6359x over previous
//
#include <hip/hip_runtime.h>
#include <hip/hip_bf16.h>

typedef unsigned short ushort_t;
typedef __attribute__((ext_vector_type(8))) short short8;
typedef __attribute__((ext_vector_type(4))) float f32x4;

// Problem constants (B=8, L=1025, E=384, H=6, D=64, WIN=33, PAD=16)
constexpr int Bc = 8;
constexpr int Lc = 1025;
constexpr int Ec = 384;
constexpr int Hc = 6;
constexpr int Dc = 64;
constexpr int MT = Bc * Lc;              // 8200 rows
constexpr int BHLD = Bc * Hc * Lc * Dc;  // 3,148,800 elems per tensor
constexpr int LT = 1032;                 // padded v_t row stride (16B-aligned rows)
constexpr float SCALE = 0.125f;          // 1/sqrt(64)
constexpr int NCH = 5;                   // cls split-K chunks of 256 keys

__device__ __forceinline__ float bf2f(ushort_t u) {
    union { unsigned int u; float f; } v; v.u = ((unsigned int)u) << 16; return v.f;
}
__device__ __forceinline__ ushort_t f2bf(float f) {
    union { float f; unsigned int u; } v; v.f = f;
    unsigned int r = v.u + 0x7FFFu + ((v.u >> 16) & 1u);
    return (ushort_t)(r >> 16);
}

#define GLOAD_LDS16(gp, lp)                                                          \
    __builtin_amdgcn_global_load_lds(                                                \
        (const __attribute__((address_space(1))) unsigned int*)(gp),                 \
        (__attribute__((address_space(3))) unsigned int*)(lp), 16, 0, 0)

// ---------------------------------------------------------------------------
// Kernel 0: merged prep.  Blocks [0, 3075): cast x fp32->bf16 (float4/thread).
// Blocks [3075, 3651): transpose+cast the 4 weight matrices.
// ---------------------------------------------------------------------------
__global__ __launch_bounds__(256) void prep_kernel(
    const float* __restrict__ x, ushort_t* __restrict__ xb,
    const float* __restrict__ Wq, const float* __restrict__ Wk,
    const float* __restrict__ Wv, const float* __restrict__ Wo,
    ushort_t* __restrict__ Wt_all)
{
    const int bid = blockIdx.x;
    if (bid < 3075) {
        int i = bid * 256 + threadIdx.x;
        float4 v = ((const float4*)x)[i];
        ushort4 o;
        o.x = f2bf(v.x); o.y = f2bf(v.y); o.z = f2bf(v.z); o.w = f2bf(v.w);
        ((ushort4*)xb)[i] = o;
        return;
    }
    __shared__ float t[32][33];
    const int b2 = bid - 3075;
    const int z = b2 / 144, rem = b2 - z * 144;
    const int yy = rem / 12, xx = rem - yy * 12;
    const float* W = (z == 0) ? Wq : (z == 1) ? Wk : (z == 2) ? Wv : Wo;
    ushort_t* Wt = Wt_all + (size_t)z * Ec * Ec;
    const int x0 = xx * 32, y0 = yy * 32;
    const int tx = threadIdx.x & 31, ty = threadIdx.x >> 5;
#pragma unroll
    for (int j = 0; j < 4; j++)
        t[ty + 8 * j][tx] = W[(size_t)(y0 + ty + 8 * j) * Ec + x0 + tx];
    __syncthreads();
#pragma unroll
    for (int j = 0; j < 4; j++)
        Wt[(size_t)(x0 + ty + 8 * j) * Ec + y0 + tx] = f2bf(t[tx][ty + 8 * j]);
}

// ---------------------------------------------------------------------------
// Kernel 1: fused QKV projection via bf16 MFMA (128x128 tile, BK=64, 4 waves).
// ---------------------------------------------------------------------------
__global__ __launch_bounds__(256) void qkv_mfma_kernel(
    const ushort_t* __restrict__ xb, const ushort_t* __restrict__ Wt,
    const float* __restrict__ bq, const float* __restrict__ bk,
    const float* __restrict__ bv, ushort_t* __restrict__ qkv)
{
    __shared__ __align__(16) ushort_t As[128 * 64];
    __shared__ __align__(16) ushort_t Bs[128 * 64];

    const int tid = threadIdx.x;
    const int lane = tid & 63;
    const int wid = tid >> 6;
    const int wr = wid >> 1, wc = wid & 1;
    const int m0 = blockIdx.x * 128;
    const int n0 = blockIdx.y * 128;
    const int which = n0 / Ec;
    const int nm0 = n0 - which * Ec;
    const ushort_t* Wmat = Wt + (size_t)which * Ec * Ec;
    const float* bias = (which == 0) ? bq : (which == 1) ? bk : bv;

    f32x4 acc[4][4];
#pragma unroll
    for (int i = 0; i < 4; i++)
#pragma unroll
        for (int j = 0; j < 4; j++) acc[i][j] = (f32x4){0.f, 0.f, 0.f, 0.f};

    for (int kt = 0; kt < Ec; kt += 64) {
#pragma unroll
        for (int c = 0; c < 4; c++) {
            int ci  = (wid * 4 + c) * 64 + lane;
            int row = ci >> 3, kc = ci & 7;
            int kcs = kc ^ (row & 7);
            int rowA = m0 + row; rowA = rowA < MT ? rowA : MT - 1;
            GLOAD_LDS16(xb + (size_t)rowA * Ec + kt + kcs * 8,
                        As + (size_t)(wid * 4 + c) * 512);
            GLOAD_LDS16(Wmat + (size_t)(nm0 + row) * Ec + kt + kcs * 8,
                        Bs + (size_t)(wid * 4 + c) * 512);
        }
        __syncthreads();

#pragma unroll
        for (int ki = 0; ki < 2; ki++) {
            short8 a[4], b[4];
            const int kchunk = ki * 4 + (lane >> 4);
#pragma unroll
            for (int mi = 0; mi < 4; mi++) {
                int row = wr * 64 + mi * 16 + (lane & 15);
                a[mi] = *(const short8*)(As + row * 64 + ((kchunk ^ (row & 7)) * 8));
            }
#pragma unroll
            for (int ni = 0; ni < 4; ni++) {
                int row = wc * 64 + ni * 16 + (lane & 15);
                b[ni] = *(const short8*)(Bs + row * 64 + ((kchunk ^ (row & 7)) * 8));
            }
#pragma unroll
            for (int mi = 0; mi < 4; mi++)
#pragma unroll
                for (int ni = 0; ni < 4; ni++)
                    acc[mi][ni] = __builtin_amdgcn_mfma_f32_16x16x32_bf16(
                        a[mi], b[ni], acc[mi][ni], 0, 0, 0);
        }
        __syncthreads();
    }

    const int colL = lane & 15;
    const int rowL = (lane >> 4) * 4;
#pragma unroll
    for (int ni = 0; ni < 4; ni++) {
        int nm = nm0 + wc * 64 + ni * 16 + colL;
        float bv_ = bias[nm];
        int h = nm >> 6, d = nm & 63;
#pragma unroll
        for (int mi = 0; mi < 4; mi++) {
#pragma unroll
            for (int r = 0; r < 4; r++) {
                int m = m0 + wr * 64 + mi * 16 + rowL + r;
                if (m < MT) {
                    int b_ = m / Lc, l = m - b_ * Lc;
                    qkv[(size_t)which * BHLD +
                        ((size_t)(b_ * Hc + h) * Lc + l) * Dc + d] =
                        f2bf(acc[mi][ni][r] + bv_);
                }
            }
        }
    }
}

// ---------------------------------------------------------------------------
// Kernel 2: fused  V-transpose  +  CLS split-K partials.
//   blockIdx.x < 17 : vT    — V (B,H,L,D) -> (B,H,D,Lpad), l0 = 64*x
//   blockIdx.x >= 17: cls   — chunk ch = x-17 (0..4), keys [ch*256, +256)
// Both read only qkv; independent; run concurrently in one dispatch.
// ---------------------------------------------------------------------------
__global__ __launch_bounds__(256) void vt_cls_kernel(
    const ushort_t* __restrict__ qkv, ushort_t* __restrict__ vt,
    float* __restrict__ part)
{
    const int bh = blockIdx.y;
    const int tid = threadIdx.x;

    if (blockIdx.x < 17) {
        // ---------------- vT branch ----------------
        __shared__ ushort_t t[64][68];
        const int l0 = blockIdx.x * 64;
        const ushort_t* V = qkv + 2 * (size_t)BHLD + (size_t)bh * Lc * Dc;
        ushort_t* vto = vt + (size_t)bh * 64 * LT;
#pragma unroll
        for (int i = 0; i < 4; i++) {
            int idx = tid + i * 256;
            int l = idx >> 4, dc = idx & 15;
            int ls = l0 + l; ls = ls > 1024 ? 1024 : ls;
            ushort4 v = *(const ushort4*)(V + (size_t)ls * Dc + dc * 4);
            *(ushort4*)&t[l][dc * 4] = v;
        }
        __syncthreads();
#pragma unroll
        for (int i = 0; i < 4; i++) {
            int idx = tid + i * 256;
            int d = idx >> 4, lc = idx & 15;
            ushort4 o;
            o.x = t[lc * 4 + 0][d]; o.y = t[lc * 4 + 1][d];
            o.z = t[lc * 4 + 2][d]; o.w = t[lc * 4 + 3][d];
            int lw = l0 + lc * 4;
            if (lw <= 1024)
                *(ushort4*)(vto + (size_t)d * LT + lw) = o;
        }
        return;
    }

    // ---------------- cls_part branch (round-3 verbatim logic) ----------------
    __shared__ float qs[64];
    __shared__ float ps[256];
    __shared__ float red[256];

    const int ch = blockIdx.x - 17;
    const int base = ch * 256;
    const int count = min(256, Lc - base);
    const ushort_t* Q = qkv + (size_t)bh * Lc * Dc;
    const ushort_t* K = Q + (size_t)BHLD;
    const ushort_t* V = Q + 2 * (size_t)BHLD;

    if (tid < 64) qs[tid] = bf2f(Q[tid]);
    __syncthreads();

    float s = -1e30f;
    if (tid < count) {
        const ushort4* kp = (const ushort4*)(K + (size_t)(base + tid) * Dc);
        float acc = 0.f;
#pragma unroll
        for (int c = 0; c < 16; c++) {
            ushort4 kv = kp[c];
            acc += qs[c * 4 + 0] * bf2f(kv.x) + qs[c * 4 + 1] * bf2f(kv.y) +
                   qs[c * 4 + 2] * bf2f(kv.z) + qs[c * 4 + 3] * bf2f(kv.w);
        }
        s = acc * SCALE;
    }
    red[tid] = s; __syncthreads();
    for (int off = 128; off > 0; off >>= 1) {
        if (tid < off) red[tid] = fmaxf(red[tid], red[tid + off]);
        __syncthreads();
    }
    const float m = red[0];
    __syncthreads();

    float p = (tid < count) ? __expf(s - m) : 0.f;
    ps[tid] = p;
    red[tid] = p; __syncthreads();
    for (int off = 128; off > 0; off >>= 1) {
        if (tid < off) red[tid] += red[tid + off];
        __syncthreads();
    }
    const float S = red[0];
    __syncthreads();

    const int d = tid & 63, sl = tid >> 6;
    float acc = 0.f;
    for (int i = sl; i < count; i += 4)
        acc += ps[i] * bf2f(V[(size_t)(base + i) * Dc + d]);
    red[tid] = acc; __syncthreads();
    if (tid < 64) {
        float o = red[tid] + red[tid + 64] + red[tid + 128] + red[tid + 192];
        float* pp = part + (size_t)(bh * NCH + ch) * 66;
        pp[2 + tid] = o;
        if (tid == 0) { pp[0] = m; pp[1] = S; }
    }
}

// ---------------------------------------------------------------------------
// Kernel 3: windowed MFMA attention + CLS combine.  grid (17, 48), 256 thr.
//   blockIdx.x < 16 : windowed attention (round-3-verbatim body)
//   blockIdx.x == 16: CLS combine (trivial: 5 partials -> attnb row 0)
// ---------------------------------------------------------------------------
__global__ __launch_bounds__(256) void win_attn_kernel(
    const ushort_t* __restrict__ qkv, const ushort_t* __restrict__ vt,
    const float* __restrict__ part, ushort_t* __restrict__ attnb)
{
    __shared__ __align__(16) ushort_t Kb[128 * 64];
    __shared__ __align__(16) ushort_t Vb[64 * 128];
    __shared__ __align__(16) ushort_t QP[64 * 128];

    const int bh = blockIdx.y;
    const int tid = threadIdx.x, lane = tid & 63, wid = tid >> 6;
    const int b_ = bh / Hc, h = bh - b_ * Hc;

    if (blockIdx.x == 16) {
        // -------- CLS combine: cheap, no straggler risk --------
        if (tid >= 64) return;
        float M = -1e30f;
#pragma unroll
        for (int ch = 0; ch < NCH; ch++)
            M = fmaxf(M, part[(size_t)(bh * NCH + ch) * 66]);
        float S = 0.f, O = 0.f;
#pragma unroll
        for (int ch = 0; ch < NCH; ch++) {
            const float* pp = part + (size_t)(bh * NCH + ch) * 66;
            float w = __expf(pp[0] - M);
            S += pp[1] * w;
            O += pp[2 + tid] * w;
        }
        attnb[(size_t)(b_ * Lc) * Ec + h * 64 + tid] = f2bf(O / S);
        return;
    }

    // -------- windowed branch (round-3 verbatim) --------
    const int t = blockIdx.x;
    const int l0 = 1 + t * 64, k0 = l0 - 17;
    const ushort_t* Qg = qkv + (size_t)bh * Lc * Dc;
    const ushort_t* Kg = Qg + (size_t)BHLD;
    const ushort_t* Vt = vt + (size_t)bh * 64 * LT;

#pragma unroll
    for (int i = 0; i < 4; i++) {
        int p = (i * 4 + wid) * 64 + lane;
        {   // K: row j, 8 chunks of 16B
            int j = p >> 3, c = p & 7, g = c ^ (j & 7);
            int kp = (j <= 111) ? min(max(k0 + j, 0), 1024) : 0;
            GLOAD_LDS16(Kg + (size_t)kp * Dc + g * 8,
                        Kb + (size_t)(i * 4 + wid) * 512);
        }
        {   // V^T: row d, 16 chunks of 8 kpos
            int d = p >> 4, jc = p & 15, g = jc ^ (d & 15);
            int kb = (g <= 13) ? max(k0 + g * 8, 0) : 0;
            GLOAD_LDS16(Vt + (size_t)d * LT + kb,
                        Vb + (size_t)(i * 4 + wid) * 512);
        }
    }
#pragma unroll
    for (int i = 0; i < 2; i++) {
        int p = (i * 4 + wid) * 64 + lane;
        int q = p >> 3, c = p & 7, g = c ^ (q & 7);
        GLOAD_LDS16(Qg + (size_t)(l0 + q) * Dc + g * 8,
                    QP + (size_t)(i * 4 + wid) * 512);
    }
    __syncthreads();

    f32x4 sacc[8];
#pragma unroll
    for (int tj = 0; tj < 8; tj++) sacc[tj] = (f32x4){0.f, 0.f, 0.f, 0.f};
#pragma unroll
    for (int ki = 0; ki < 2; ki++) {
        const int gc = ki * 4 + (lane >> 4);
        const int qrow = wid * 16 + (lane & 15);
        short8 a = *(const short8*)(QP + qrow * 64 + ((gc ^ (qrow & 7)) * 8));
#pragma unroll
        for (int tj = 0; tj < 8; tj++) {
            int jrow = tj * 16 + (lane & 15);
            short8 b = *(const short8*)(Kb + jrow * 64 + ((gc ^ (jrow & 7)) * 8));
            sacc[tj] = __builtin_amdgcn_mfma_f32_16x16x32_bf16(a, b, sacc[tj], 0, 0, 0);
        }
    }
    __syncthreads();   // Q region dead; P may overwrite it

    const int qb = wid * 16 + (lane >> 4) * 4;
    const int cl = lane & 15;
    float inv[4];
#pragma unroll
    for (int r = 0; r < 4; r++) {
        const int q = qb + r;
        float sv[8];
        float mx = -1e30f;
#pragma unroll
        for (int tj = 0; tj < 8; tj++) {
            int j = tj * 16 + cl;
            int kp = k0 + j;
            bool valid = (j == 112) ||
                         ((j >= q + 1) && (j <= q + 33) && (kp >= 1) && (kp <= 1024));
            float s = valid ? sacc[tj][r] * SCALE : -1e30f;
            sv[tj] = s;
            mx = fmaxf(mx, s);
        }
        mx = fmaxf(mx, __shfl_xor(mx, 1));
        mx = fmaxf(mx, __shfl_xor(mx, 2));
        mx = fmaxf(mx, __shfl_xor(mx, 4));
        mx = fmaxf(mx, __shfl_xor(mx, 8));
        float sum = 0.f;
#pragma unroll
        for (int tj = 0; tj < 8; tj++) {
            float pv = __expf(sv[tj] - mx);
            sv[tj] = pv;
            sum += pv;
        }
        sum += __shfl_xor(sum, 1);
        sum += __shfl_xor(sum, 2);
        sum += __shfl_xor(sum, 4);
        sum += __shfl_xor(sum, 8);
        inv[r] = 1.f / sum;
#pragma unroll
        for (int tj = 0; tj < 8; tj++) {
            int j = tj * 16 + cl;
            QP[q * 128 + (((j >> 3) ^ (q & 15)) * 8) + (j & 7)] = f2bf(sv[tj]);
        }
    }
    __syncthreads();

    f32x4 oacc[4];
#pragma unroll
    for (int dt = 0; dt < 4; dt++) oacc[dt] = (f32x4){0.f, 0.f, 0.f, 0.f};
#pragma unroll
    for (int kc = 0; kc < 4; kc++) {
        const int gc = kc * 4 + (lane >> 4);
        const int qrow = wid * 16 + (lane & 15);
        short8 pa = *(const short8*)(QP + qrow * 128 + ((gc ^ (qrow & 15)) * 8));
#pragma unroll
        for (int dt = 0; dt < 4; dt++) {
            int drow = dt * 16 + (lane & 15);
            short8 vb = *(const short8*)(Vb + drow * 128 + ((gc ^ (drow & 15)) * 8));
            oacc[dt] = __builtin_amdgcn_mfma_f32_16x16x32_bf16(pa, vb, oacc[dt], 0, 0, 0);
        }
    }

#pragma unroll
    for (int dt = 0; dt < 4; dt++) {
        int d = dt * 16 + cl;
#pragma unroll
        for (int r = 0; r < 4; r++) {
            int l = l0 + qb + r;
            attnb[(size_t)(b_ * Lc + l) * Ec + h * 64 + d] = f2bf(oacc[dt][r] * inv[r]);
        }
    }
}

// ---------------------------------------------------------------------------
// Kernel 4: output projection via bf16 MFMA, 64x128 tile (grid 129 x 3).
// ---------------------------------------------------------------------------
__global__ __launch_bounds__(256) void out_mfma_kernel(
    const ushort_t* __restrict__ attn_rows, const ushort_t* __restrict__ Wot,
    const float* __restrict__ bo, float* __restrict__ out)
{
    __shared__ __align__(16) ushort_t As[64 * 64];
    __shared__ __align__(16) ushort_t Bs[128 * 64];

    const int tid = threadIdx.x;
    const int lane = tid & 63;
    const int wid = tid >> 6;
    const int wr = wid & 1, wc = wid >> 1;
    const int m0 = blockIdx.x * 64;
    const int n0 = blockIdx.y * 128;

    f32x4 acc[2][4];
#pragma unroll
    for (int i = 0; i < 2; i++)
#pragma unroll
        for (int j = 0; j < 4; j++) acc[i][j] = (f32x4){0.f, 0.f, 0.f, 0.f};

    for (int kt = 0; kt < Ec; kt += 64) {
#pragma unroll
        for (int c = 0; c < 2; c++) {       // A: 64x64 = 512 chunks
            int ci  = (wid * 2 + c) * 64 + lane;
            int row = ci >> 3, kc = ci & 7;
            int kcs = kc ^ (row & 7);
            int rowA = m0 + row; rowA = rowA < MT ? rowA : MT - 1;
            GLOAD_LDS16(attn_rows + (size_t)rowA * Ec + kt + kcs * 8,
                        As + (size_t)(wid * 2 + c) * 512);
        }
#pragma unroll
        for (int c = 0; c < 4; c++) {       // B: 128x64 = 1024 chunks
            int ci  = (wid * 4 + c) * 64 + lane;
            int row = ci >> 3, kc = ci & 7;
            int kcs = kc ^ (row & 7);
            GLOAD_LDS16(Wot + (size_t)(n0 + row) * Ec + kt + kcs * 8,
                        Bs + (size_t)(wid * 4 + c) * 512);
        }
        __syncthreads();

#pragma unroll
        for (int ki = 0; ki < 2; ki++) {
            short8 a[2], b[4];
            const int kchunk = ki * 4 + (lane >> 4);
#pragma unroll
            for (int mi = 0; mi < 2; mi++) {
                int row = wr * 32 + mi * 16 + (lane & 15);
                a[mi] = *(const short8*)(As + row * 64 + ((kchunk ^ (row & 7)) * 8));
            }
#pragma unroll
            for (int ni = 0; ni < 4; ni++) {
                int row = wc * 64 + ni * 16 + (lane & 15);
                b[ni] = *(const short8*)(Bs + row * 64 + ((kchunk ^ (row & 7)) * 8));
            }
#pragma unroll
            for (int mi = 0; mi < 2; mi++)
#pragma unroll
                for (int ni = 0; ni < 4; ni++)
                    acc[mi][ni] = __builtin_amdgcn_mfma_f32_16x16x32_bf16(
                        a[mi], b[ni], acc[mi][ni], 0, 0, 0);
        }
        __syncthreads();
    }

    const int colL = lane & 15;
    const int rowL = (lane >> 4) * 4;
#pragma unroll
    for (int ni = 0; ni < 4; ni++) {
        int n = n0 + wc * 64 + ni * 16 + colL;
        float bo_v = bo[n];
#pragma unroll
        for (int mi = 0; mi < 2; mi++) {
#pragma unroll
            for (int r = 0; r < 4; r++) {
                int m = m0 + wr * 32 + mi * 16 + rowL + r;
                if (m < MT) out[(size_t)m * Ec + n] = acc[mi][ni][r] + bo_v;
            }
        }
    }
}

// ---------------------------------------------------------------------------
extern "C" void kernel_launch(void* const* d_in, const int* in_sizes, int n_in,
                              void* d_out, int out_size, void* d_ws, size_t ws_size,
                              hipStream_t stream)
{
    const float* x  = (const float*)d_in[0];
    const float* Wq = (const float*)d_in[1];
    const float* bq = (const float*)d_in[2];
    const float* Wk = (const float*)d_in[3];
    const float* bk = (const float*)d_in[4];
    const float* Wv = (const float*)d_in[5];
    const float* bv = (const float*)d_in[6];
    const float* Wo = (const float*)d_in[7];
    const float* bo = (const float*)d_in[8];
    float* out = (float*)d_out;

    // ws layout (ushort units, all 16B-aligned):
    // xb | Wt(4) | qkv(3) | v_t | attnb | clsp(float)  ~= 39 MB
    ushort_t* xb    = (ushort_t*)d_ws;
    ushort_t* Wt    = xb + (size_t)MT * Ec;                  // 3,148,800
    ushort_t* qkvb  = Wt + (size_t)4 * Ec * Ec;              // + 589,824
    ushort_t* vtb   = qkvb + (size_t)3 * BHLD;               // + 9,446,400
    ushort_t* attnb = vtb + (size_t)Bc * Hc * 64 * LT;       // + 3,170,304
    float* clsp     = (float*)(attnb + (size_t)MT * Ec);     // + 3,148,800

    prep_kernel<<<3075 + 576, 256, 0, stream>>>(x, xb, Wq, Wk, Wv, Wo, Wt);

    qkv_mfma_kernel<<<dim3((MT + 127) / 128, 9), 256, 0, stream>>>(
        xb, Wt, bq, bk, bv, qkvb);

    vt_cls_kernel<<<dim3(17 + NCH, Bc * Hc), 256, 0, stream>>>(qkvb, vtb, clsp);

    win_attn_kernel<<<dim3(17, Bc * Hc), 256, 0, stream>>>(qkvb, vtb, clsp, attnb);

    out_mfma_kernel<<<dim3((MT + 63) / 64, 3), 256, 0, stream>>>(
        attnb, Wt + (size_t)3 * Ec * Ec, bo, out);
}

// Round 7
// 163.876 us; speedup vs baseline: 1.6493x; 1.0082x over previous
//
#include <hip/hip_runtime.h>
#include <hip/hip_bf16.h>

typedef unsigned short ushort_t;
typedef __attribute__((ext_vector_type(8))) short short8;
typedef __attribute__((ext_vector_type(4))) float f32x4;

// Problem constants (B=8, L=1025, E=384, H=6, D=64, WIN=33, PAD=16)
constexpr int Bc = 8;
constexpr int Lc = 1025;
constexpr int Ec = 384;
constexpr int Hc = 6;
constexpr int Dc = 64;
constexpr int MT = Bc * Lc;              // 8200 rows
constexpr int BHLD = Bc * Hc * Lc * Dc;  // 3,148,800 elems per tensor
constexpr float SCALE = 0.125f;          // 1/sqrt(64)
constexpr int NCH = 5;                   // cls split-K chunks of 256 keys

__device__ __forceinline__ float bf2f(ushort_t u) {
    union { unsigned int u; float f; } v; v.u = ((unsigned int)u) << 16; return v.f;
}
__device__ __forceinline__ ushort_t f2bf(float f) {
    union { float f; unsigned int u; } v; v.f = f;
    unsigned int r = v.u + 0x7FFFu + ((v.u >> 16) & 1u);
    return (ushort_t)(r >> 16);
}

#define GLOAD_LDS16(gp, lp)                                                          \
    __builtin_amdgcn_global_load_lds(                                                \
        (const __attribute__((address_space(1))) unsigned int*)(gp),                 \
        (__attribute__((address_space(3))) unsigned int*)(lp), 16, 0, 0)

// ---------------------------------------------------------------------------
// Kernel 0: merged prep.  Blocks [0, 3075): cast x fp32->bf16 (float4/thread).
// Blocks [3075, 3651): transpose+cast the 4 weight matrices.
// ---------------------------------------------------------------------------
__global__ __launch_bounds__(256) void prep_kernel(
    const float* __restrict__ x, ushort_t* __restrict__ xb,
    const float* __restrict__ Wq, const float* __restrict__ Wk,
    const float* __restrict__ Wv, const float* __restrict__ Wo,
    ushort_t* __restrict__ Wt_all)
{
    const int bid = blockIdx.x;
    if (bid < 3075) {
        int i = bid * 256 + threadIdx.x;
        float4 v = ((const float4*)x)[i];
        ushort4 o;
        o.x = f2bf(v.x); o.y = f2bf(v.y); o.z = f2bf(v.z); o.w = f2bf(v.w);
        ((ushort4*)xb)[i] = o;
        return;
    }
    __shared__ float t[32][33];
    const int b2 = bid - 3075;
    const int z = b2 / 144, rem = b2 - z * 144;
    const int yy = rem / 12, xx = rem - yy * 12;
    const float* W = (z == 0) ? Wq : (z == 1) ? Wk : (z == 2) ? Wv : Wo;
    ushort_t* Wt = Wt_all + (size_t)z * Ec * Ec;
    const int x0 = xx * 32, y0 = yy * 32;
    const int tx = threadIdx.x & 31, ty = threadIdx.x >> 5;
#pragma unroll
    for (int j = 0; j < 4; j++)
        t[ty + 8 * j][tx] = W[(size_t)(y0 + ty + 8 * j) * Ec + x0 + tx];
    __syncthreads();
#pragma unroll
    for (int j = 0; j < 4; j++)
        Wt[(size_t)(x0 + ty + 8 * j) * Ec + y0 + tx] = f2bf(t[tx][ty + 8 * j]);
}

// ---------------------------------------------------------------------------
// Kernel 1: fused QKV projection via bf16 MFMA (128x128 tile, BK=64, 4 waves).
// ---------------------------------------------------------------------------
__global__ __launch_bounds__(256) void qkv_mfma_kernel(
    const ushort_t* __restrict__ xb, const ushort_t* __restrict__ Wt,
    const float* __restrict__ bq, const float* __restrict__ bk,
    const float* __restrict__ bv, ushort_t* __restrict__ qkv)
{
    __shared__ __align__(16) ushort_t As[128 * 64];
    __shared__ __align__(16) ushort_t Bs[128 * 64];

    const int tid = threadIdx.x;
    const int lane = tid & 63;
    const int wid = tid >> 6;
    const int wr = wid >> 1, wc = wid & 1;
    const int m0 = blockIdx.x * 128;
    const int n0 = blockIdx.y * 128;
    const int which = n0 / Ec;
    const int nm0 = n0 - which * Ec;
    const ushort_t* Wmat = Wt + (size_t)which * Ec * Ec;
    const float* bias = (which == 0) ? bq : (which == 1) ? bk : bv;

    f32x4 acc[4][4];
#pragma unroll
    for (int i = 0; i < 4; i++)
#pragma unroll
        for (int j = 0; j < 4; j++) acc[i][j] = (f32x4){0.f, 0.f, 0.f, 0.f};

    for (int kt = 0; kt < Ec; kt += 64) {
#pragma unroll
        for (int c = 0; c < 4; c++) {
            int ci  = (wid * 4 + c) * 64 + lane;
            int row = ci >> 3, kc = ci & 7;
            int kcs = kc ^ (row & 7);
            int rowA = m0 + row; rowA = rowA < MT ? rowA : MT - 1;
            GLOAD_LDS16(xb + (size_t)rowA * Ec + kt + kcs * 8,
                        As + (size_t)(wid * 4 + c) * 512);
            GLOAD_LDS16(Wmat + (size_t)(nm0 + row) * Ec + kt + kcs * 8,
                        Bs + (size_t)(wid * 4 + c) * 512);
        }
        __syncthreads();

#pragma unroll
        for (int ki = 0; ki < 2; ki++) {
            short8 a[4], b[4];
            const int kchunk = ki * 4 + (lane >> 4);
#pragma unroll
            for (int mi = 0; mi < 4; mi++) {
                int row = wr * 64 + mi * 16 + (lane & 15);
                a[mi] = *(const short8*)(As + row * 64 + ((kchunk ^ (row & 7)) * 8));
            }
#pragma unroll
            for (int ni = 0; ni < 4; ni++) {
                int row = wc * 64 + ni * 16 + (lane & 15);
                b[ni] = *(const short8*)(Bs + row * 64 + ((kchunk ^ (row & 7)) * 8));
            }
#pragma unroll
            for (int mi = 0; mi < 4; mi++)
#pragma unroll
                for (int ni = 0; ni < 4; ni++)
                    acc[mi][ni] = __builtin_amdgcn_mfma_f32_16x16x32_bf16(
                        a[mi], b[ni], acc[mi][ni], 0, 0, 0);
        }
        __syncthreads();
    }

    const int colL = lane & 15;
    const int rowL = (lane >> 4) * 4;
#pragma unroll
    for (int ni = 0; ni < 4; ni++) {
        int nm = nm0 + wc * 64 + ni * 16 + colL;
        float bv_ = bias[nm];
        int h = nm >> 6, d = nm & 63;
#pragma unroll
        for (int mi = 0; mi < 4; mi++) {
#pragma unroll
            for (int r = 0; r < 4; r++) {
                int m = m0 + wr * 64 + mi * 16 + rowL + r;
                if (m < MT) {
                    int b_ = m / Lc, l = m - b_ * Lc;
                    qkv[(size_t)which * BHLD +
                        ((size_t)(b_ * Hc + h) * Lc + l) * Dc + d] =
                        f2bf(acc[mi][ni][r] + bv_);
                }
            }
        }
    }
}

// ---------------------------------------------------------------------------
// Kernel 2: CLS split-K partials (round-3-verbatim). grid (48, NCH).
// ---------------------------------------------------------------------------
__global__ __launch_bounds__(256) void cls_part_kernel(
    const ushort_t* __restrict__ qkv, float* __restrict__ part)
{
    const int bh = blockIdx.x, ch = blockIdx.y;
    const int base = ch * 256;
    const int count = min(256, Lc - base);
    const ushort_t* Q = qkv + (size_t)bh * Lc * Dc;
    const ushort_t* K = Q + (size_t)BHLD;
    const ushort_t* V = Q + 2 * (size_t)BHLD;

    __shared__ float qs[64];
    __shared__ float ps[256];
    __shared__ float red[256];

    const int tid = threadIdx.x;
    if (tid < 64) qs[tid] = bf2f(Q[tid]);
    __syncthreads();

    float s = -1e30f;
    if (tid < count) {
        const ushort4* kp = (const ushort4*)(K + (size_t)(base + tid) * Dc);
        float acc = 0.f;
#pragma unroll
        for (int c = 0; c < 16; c++) {
            ushort4 kv = kp[c];
            acc += qs[c * 4 + 0] * bf2f(kv.x) + qs[c * 4 + 1] * bf2f(kv.y) +
                   qs[c * 4 + 2] * bf2f(kv.z) + qs[c * 4 + 3] * bf2f(kv.w);
        }
        s = acc * SCALE;
    }
    red[tid] = s; __syncthreads();
    for (int off = 128; off > 0; off >>= 1) {
        if (tid < off) red[tid] = fmaxf(red[tid], red[tid + off]);
        __syncthreads();
    }
    const float m = red[0];
    __syncthreads();

    float p = (tid < count) ? __expf(s - m) : 0.f;
    ps[tid] = p;
    red[tid] = p; __syncthreads();
    for (int off = 128; off > 0; off >>= 1) {
        if (tid < off) red[tid] += red[tid + off];
        __syncthreads();
    }
    const float S = red[0];
    __syncthreads();

    const int d = tid & 63, sl = tid >> 6;
    float acc = 0.f;
    for (int i = sl; i < count; i += 4)
        acc += ps[i] * bf2f(V[(size_t)(base + i) * Dc + d]);
    red[tid] = acc; __syncthreads();
    if (tid < 64) {
        float o = red[tid] + red[tid + 64] + red[tid + 128] + red[tid + 192];
        float* pp = part + (size_t)(bh * NCH + ch) * 66;
        pp[2 + tid] = o;
        if (tid == 0) { pp[0] = m; pp[1] = S; }
    }
}

// ---------------------------------------------------------------------------
// Kernel 3: windowed MFMA attention (NT=7 j-tiles, in-kernel V transpose)
//           + CLS combine.  grid (17, 48), 256 threads (4 waves).
//   blockIdx.x < 16 : 64 queries, 112 key slots: j in [0,95] -> kpos=(l0-16)+j
//                     (band for query q: j in [q, q+32]); j==96 -> CLS;
//                     j in 97..111 masked.  V staged global->reg->transposed
//                     LDS write (no vT kernel, no vtb buffer).
//   blockIdx.x == 16: CLS combine from split-K partials.
// ---------------------------------------------------------------------------
__global__ __launch_bounds__(256) void win_attn_kernel(
    const ushort_t* __restrict__ qkv, const float* __restrict__ part,
    ushort_t* __restrict__ attnb)
{
    __shared__ __align__(16) ushort_t Kb[128 * 64];   // K rows 0..111 used
    __shared__ __align__(16) ushort_t Vb[64 * 128];   // V^T, chunk-xor (d&15)
    __shared__ __align__(16) ushort_t QP[64 * 128];   // Q (8KB) then P (16KB)

    const int bh = blockIdx.y;
    const int tid = threadIdx.x, lane = tid & 63, wid = tid >> 6;
    const int b_ = bh / Hc, h = bh - b_ * Hc;

    if (blockIdx.x == 16) {
        // -------- CLS combine --------
        if (tid >= 64) return;
        float M = -1e30f;
#pragma unroll
        for (int ch = 0; ch < NCH; ch++)
            M = fmaxf(M, part[(size_t)(bh * NCH + ch) * 66]);
        float S = 0.f, O = 0.f;
#pragma unroll
        for (int ch = 0; ch < NCH; ch++) {
            const float* pp = part + (size_t)(bh * NCH + ch) * 66;
            float w = __expf(pp[0] - M);
            S += pp[1] * w;
            O += pp[2 + tid] * w;
        }
        attnb[(size_t)(b_ * Lc) * Ec + h * 64 + tid] = f2bf(O / S);
        return;
    }

    // -------- windowed branch --------
    const int t = blockIdx.x;
    const int l0 = 1 + t * 64;
    const int k0n = l0 - 16;            // slot j -> kpos k0n + j (j <= 95)
    const ushort_t* Qg = qkv + (size_t)bh * Lc * Dc;
    const ushort_t* Kg = Qg + (size_t)BHLD;
    const ushort_t* Vg = Qg + 2 * (size_t)BHLD;

    // V: global -> regs (112 rows x 8 d-chunks of 16B = 896 chunks)
    short8 vreg[4];
    int vrow[4], vdc[4];
#pragma unroll
    for (int i = 0; i < 4; i++) {
        int ci = i * 256 + tid;
        if (ci < 896) {
            int j = ci >> 3, dc = ci & 7;
            int kp = (j <= 95) ? min(max(k0n + j, 0), 1024) : 0;
            vreg[i] = *(const short8*)(Vg + (size_t)kp * Dc + dc * 8);
            vrow[i] = j; vdc[i] = dc;
        } else { vrow[i] = -1; vdc[i] = 0; }
    }

    // K rows 0..111 (14 wave-chunks) + Q rows 0..63 via global_load_lds
#pragma unroll
    for (int i = 0; i < 4; i++) {
        int wchunk = i * 4 + wid;        // 0..15; K needs 0..13 (uniform/wave)
        if (wchunk < 14) {
            int p = wchunk * 64 + lane;
            int j = p >> 3, c = p & 7, g = c ^ (j & 7);
            int kp = (j <= 95) ? min(max(k0n + j, 0), 1024) : 0;
            GLOAD_LDS16(Kg + (size_t)kp * Dc + g * 8,
                        Kb + (size_t)wchunk * 512);
        }
    }
#pragma unroll
    for (int i = 0; i < 2; i++) {
        int p = (i * 4 + wid) * 64 + lane;
        int q = p >> 3, c = p & 7, g = c ^ (q & 7);
        GLOAD_LDS16(Qg + (size_t)(l0 + q) * Dc + g * 8,
                    QP + (size_t)(i * 4 + wid) * 512);
    }

    // V: regs -> transposed LDS (Vb[d][j], chunk-xor (d&15))
#pragma unroll
    for (int i = 0; i < 4; i++) {
        if (vrow[i] >= 0) {
            int j = vrow[i], jc3 = j >> 3, j7 = j & 7;
#pragma unroll
            for (int z = 0; z < 8; z++) {
                int d = vdc[i] * 8 + z;
                Vb[d * 128 + ((jc3 ^ (d & 15)) * 8) + j7] = (ushort_t)vreg[i][z];
            }
        }
    }
    // zero logical chunks 14,15 of every Vb row (slots 112..127)
    if (tid < 128) {
        int d = tid >> 1, lcn = 14 + (tid & 1);
        *(short8*)(Vb + d * 128 + ((lcn ^ (d & 15)) * 8)) =
            (short8){0, 0, 0, 0, 0, 0, 0, 0};
    }
    __syncthreads();

    // ---- QK^T: wave owns q-tile wid (16 rows) x 7 j-tiles ----
    f32x4 sacc[7];
#pragma unroll
    for (int tj = 0; tj < 7; tj++) sacc[tj] = (f32x4){0.f, 0.f, 0.f, 0.f};
#pragma unroll
    for (int ki = 0; ki < 2; ki++) {
        const int gc = ki * 4 + (lane >> 4);
        const int qrow = wid * 16 + (lane & 15);
        short8 a = *(const short8*)(QP + qrow * 64 + ((gc ^ (qrow & 7)) * 8));
#pragma unroll
        for (int tj = 0; tj < 7; tj++) {
            int jrow = tj * 16 + (lane & 15);
            short8 b = *(const short8*)(Kb + jrow * 64 + ((gc ^ (jrow & 7)) * 8));
            sacc[tj] = __builtin_amdgcn_mfma_f32_16x16x32_bf16(a, b, sacc[tj], 0, 0, 0);
        }
    }
    __syncthreads();   // Q region dead; P may overwrite it

    // ---- softmax (rows q = wid*16 + (lane>>4)*4 + r), write P to LDS ----
    const int qb = wid * 16 + (lane >> 4) * 4;
    const int cl = lane & 15;
    float inv[4];
#pragma unroll
    for (int r = 0; r < 4; r++) {
        const int q = qb + r;
        float sv[7];
        float mx = -1e30f;
#pragma unroll
        for (int tj = 0; tj < 7; tj++) {
            int j = tj * 16 + cl;
            int kp = k0n + j;
            bool valid = (j == 96) ||
                         ((j >= q) && (j <= q + 32) && (kp >= 1) && (kp <= 1024));
            float s = valid ? sacc[tj][r] * SCALE : -1e30f;
            sv[tj] = s;
            mx = fmaxf(mx, s);
        }
        mx = fmaxf(mx, __shfl_xor(mx, 1));
        mx = fmaxf(mx, __shfl_xor(mx, 2));
        mx = fmaxf(mx, __shfl_xor(mx, 4));
        mx = fmaxf(mx, __shfl_xor(mx, 8));
        float sum = 0.f;
#pragma unroll
        for (int tj = 0; tj < 7; tj++) {
            float pv = __expf(sv[tj] - mx);
            sv[tj] = pv;
            sum += pv;
        }
        sum += __shfl_xor(sum, 1);
        sum += __shfl_xor(sum, 2);
        sum += __shfl_xor(sum, 4);
        sum += __shfl_xor(sum, 8);
        inv[r] = 1.f / sum;
#pragma unroll
        for (int tj = 0; tj < 7; tj++) {
            int j = tj * 16 + cl;
            QP[q * 128 + (((j >> 3) ^ (q & 15)) * 8) + (j & 7)] = f2bf(sv[tj]);
        }
    }
    // zero P logical chunks 14,15 (slots 112..127) for this thread's rows
    if (cl == 0) {
#pragma unroll
        for (int r = 0; r < 4; r++) {
            int q = qb + r;
            *(short8*)(QP + q * 128 + ((14 ^ (q & 15)) * 8)) =
                (short8){0, 0, 0, 0, 0, 0, 0, 0};
            *(short8*)(QP + q * 128 + ((15 ^ (q & 15)) * 8)) =
                (short8){0, 0, 0, 0, 0, 0, 0, 0};
        }
    }
    __syncthreads();

    // ---- PV: O(16x64) per wave = 4 k-steps x 4 d-tiles ----
    f32x4 oacc[4];
#pragma unroll
    for (int dt = 0; dt < 4; dt++) oacc[dt] = (f32x4){0.f, 0.f, 0.f, 0.f};
#pragma unroll
    for (int kc = 0; kc < 4; kc++) {
        const int gc = kc * 4 + (lane >> 4);
        const int qrow = wid * 16 + (lane & 15);
        short8 pa = *(const short8*)(QP + qrow * 128 + ((gc ^ (qrow & 15)) * 8));
#pragma unroll
        for (int dt = 0; dt < 4; dt++) {
            int drow = dt * 16 + (lane & 15);
            short8 vb = *(const short8*)(Vb + drow * 128 + ((gc ^ (drow & 15)) * 8));
            oacc[dt] = __builtin_amdgcn_mfma_f32_16x16x32_bf16(pa, vb, oacc[dt], 0, 0, 0);
        }
    }

    // ---- epilogue ----
#pragma unroll
    for (int dt = 0; dt < 4; dt++) {
        int d = dt * 16 + cl;
#pragma unroll
        for (int r = 0; r < 4; r++) {
            int l = l0 + qb + r;
            attnb[(size_t)(b_ * Lc + l) * Ec + h * 64 + d] = f2bf(oacc[dt][r] * inv[r]);
        }
    }
}

// ---------------------------------------------------------------------------
// Kernel 4: output projection via bf16 MFMA, 64x128 tile (grid 129 x 3).
// ---------------------------------------------------------------------------
__global__ __launch_bounds__(256) void out_mfma_kernel(
    const ushort_t* __restrict__ attn_rows, const ushort_t* __restrict__ Wot,
    const float* __restrict__ bo, float* __restrict__ out)
{
    __shared__ __align__(16) ushort_t As[64 * 64];
    __shared__ __align__(16) ushort_t Bs[128 * 64];

    const int tid = threadIdx.x;
    const int lane = tid & 63;
    const int wid = tid >> 6;
    const int wr = wid & 1, wc = wid >> 1;
    const int m0 = blockIdx.x * 64;
    const int n0 = blockIdx.y * 128;

    f32x4 acc[2][4];
#pragma unroll
    for (int i = 0; i < 2; i++)
#pragma unroll
        for (int j = 0; j < 4; j++) acc[i][j] = (f32x4){0.f, 0.f, 0.f, 0.f};

    for (int kt = 0; kt < Ec; kt += 64) {
#pragma unroll
        for (int c = 0; c < 2; c++) {       // A: 64x64 = 512 chunks
            int ci  = (wid * 2 + c) * 64 + lane;
            int row = ci >> 3, kc = ci & 7;
            int kcs = kc ^ (row & 7);
            int rowA = m0 + row; rowA = rowA < MT ? rowA : MT - 1;
            GLOAD_LDS16(attn_rows + (size_t)rowA * Ec + kt + kcs * 8,
                        As + (size_t)(wid * 2 + c) * 512);
        }
#pragma unroll
        for (int c = 0; c < 4; c++) {       // B: 128x64 = 1024 chunks
            int ci  = (wid * 4 + c) * 64 + lane;
            int row = ci >> 3, kc = ci & 7;
            int kcs = kc ^ (row & 7);
            GLOAD_LDS16(Wot + (size_t)(n0 + row) * Ec + kt + kcs * 8,
                        Bs + (size_t)(wid * 4 + c) * 512);
        }
        __syncthreads();

#pragma unroll
        for (int ki = 0; ki < 2; ki++) {
            short8 a[2], b[4];
            const int kchunk = ki * 4 + (lane >> 4);
#pragma unroll
            for (int mi = 0; mi < 2; mi++) {
                int row = wr * 32 + mi * 16 + (lane & 15);
                a[mi] = *(const short8*)(As + row * 64 + ((kchunk ^ (row & 7)) * 8));
            }
#pragma unroll
            for (int ni = 0; ni < 4; ni++) {
                int row = wc * 64 + ni * 16 + (lane & 15);
                b[ni] = *(const short8*)(Bs + row * 64 + ((kchunk ^ (row & 7)) * 8));
            }
#pragma unroll
            for (int mi = 0; mi < 2; mi++)
#pragma unroll
                for (int ni = 0; ni < 4; ni++)
                    acc[mi][ni] = __builtin_amdgcn_mfma_f32_16x16x32_bf16(
                        a[mi], b[ni], acc[mi][ni], 0, 0, 0);
        }
        __syncthreads();
    }

    const int colL = lane & 15;
    const int rowL = (lane >> 4) * 4;
#pragma unroll
    for (int ni = 0; ni < 4; ni++) {
        int n = n0 + wc * 64 + ni * 16 + colL;
        float bo_v = bo[n];
#pragma unroll
        for (int mi = 0; mi < 2; mi++) {
#pragma unroll
            for (int r = 0; r < 4; r++) {
                int m = m0 + wr * 32 + mi * 16 + rowL + r;
                if (m < MT) out[(size_t)m * Ec + n] = acc[mi][ni][r] + bo_v;
            }
        }
    }
}

// ---------------------------------------------------------------------------
extern "C" void kernel_launch(void* const* d_in, const int* in_sizes, int n_in,
                              void* d_out, int out_size, void* d_ws, size_t ws_size,
                              hipStream_t stream)
{
    const float* x  = (const float*)d_in[0];
    const float* Wq = (const float*)d_in[1];
    const float* bq = (const float*)d_in[2];
    const float* Wk = (const float*)d_in[3];
    const float* bk = (const float*)d_in[4];
    const float* Wv = (const float*)d_in[5];
    const float* bv = (const float*)d_in[6];
    const float* Wo = (const float*)d_in[7];
    const float* bo = (const float*)d_in[8];
    float* out = (float*)d_out;

    // ws layout (ushort units, all 16B-aligned):
    // xb | Wt(4) | qkv(3) | attnb | clsp(float)  ~= 26 MB
    ushort_t* xb    = (ushort_t*)d_ws;
    ushort_t* Wt    = xb + (size_t)MT * Ec;                  // 3,148,800
    ushort_t* qkvb  = Wt + (size_t)4 * Ec * Ec;              // + 589,824
    ushort_t* attnb = qkvb + (size_t)3 * BHLD;               // + 9,446,400
    float* clsp     = (float*)(attnb + (size_t)MT * Ec);     // + 3,148,800

    prep_kernel<<<3075 + 576, 256, 0, stream>>>(x, xb, Wq, Wk, Wv, Wo, Wt);

    qkv_mfma_kernel<<<dim3((MT + 127) / 128, 9), 256, 0, stream>>>(
        xb, Wt, bq, bk, bv, qkvb);

    cls_part_kernel<<<dim3(Bc * Hc, NCH), 256, 0, stream>>>(qkvb, clsp);

    win_attn_kernel<<<dim3(17, Bc * Hc), 256, 0, stream>>>(qkvb, clsp, attnb);

    out_mfma_kernel<<<dim3((MT + 63) / 64, 3), 256, 0, stream>>>(
        attnb, Wt + (size_t)3 * Ec * Ec, bo, out);
}

// Round 8
// 160.324 us; speedup vs baseline: 1.6859x; 1.0222x over previous
//
#include <hip/hip_runtime.h>
#include <hip/hip_bf16.h>

typedef unsigned short ushort_t;
typedef __attribute__((ext_vector_type(8))) short short8;
typedef __attribute__((ext_vector_type(4))) float f32x4;

// Problem constants (B=8, L=1025, E=384, H=6, D=64, WIN=33, PAD=16)
constexpr int Bc = 8;
constexpr int Lc = 1025;
constexpr int Ec = 384;
constexpr int Hc = 6;
constexpr int Dc = 64;
constexpr int MT = Bc * Lc;              // 8200 rows
constexpr int BHLD = Bc * Hc * Lc * Dc;  // 3,148,800 elems per tensor
constexpr float SCALE = 0.125f;          // 1/sqrt(64)
constexpr int NCH = 5;                   // cls split-K chunks of 256 keys

__device__ __forceinline__ float bf2f(ushort_t u) {
    union { unsigned int u; float f; } v; v.u = ((unsigned int)u) << 16; return v.f;
}
__device__ __forceinline__ ushort_t f2bf(float f) {
    union { float f; unsigned int u; } v; v.f = f;
    unsigned int r = v.u + 0x7FFFu + ((v.u >> 16) & 1u);
    return (ushort_t)(r >> 16);
}

#define GLOAD_LDS16(gp, lp)                                                          \
    __builtin_amdgcn_global_load_lds(                                                \
        (const __attribute__((address_space(1))) unsigned int*)(gp),                 \
        (__attribute__((address_space(3))) unsigned int*)(lp), 16, 0, 0)

// ---------------------------------------------------------------------------
// Kernel 0: merged prep.  Blocks [0, 3075): cast x fp32->bf16 (float4/thread).
// Blocks [3075, 3651): transpose+cast the 4 weight matrices.
// ---------------------------------------------------------------------------
__global__ __launch_bounds__(256) void prep_kernel(
    const float* __restrict__ x, ushort_t* __restrict__ xb,
    const float* __restrict__ Wq, const float* __restrict__ Wk,
    const float* __restrict__ Wv, const float* __restrict__ Wo,
    ushort_t* __restrict__ Wt_all)
{
    const int bid = blockIdx.x;
    if (bid < 3075) {
        int i = bid * 256 + threadIdx.x;
        float4 v = ((const float4*)x)[i];
        ushort4 o;
        o.x = f2bf(v.x); o.y = f2bf(v.y); o.z = f2bf(v.z); o.w = f2bf(v.w);
        ((ushort4*)xb)[i] = o;
        return;
    }
    __shared__ float t[32][33];
    const int b2 = bid - 3075;
    const int z = b2 / 144, rem = b2 - z * 144;
    const int yy = rem / 12, xx = rem - yy * 12;
    const float* W = (z == 0) ? Wq : (z == 1) ? Wk : (z == 2) ? Wv : Wo;
    ushort_t* Wt = Wt_all + (size_t)z * Ec * Ec;
    const int x0 = xx * 32, y0 = yy * 32;
    const int tx = threadIdx.x & 31, ty = threadIdx.x >> 5;
#pragma unroll
    for (int j = 0; j < 4; j++)
        t[ty + 8 * j][tx] = W[(size_t)(y0 + ty + 8 * j) * Ec + x0 + tx];
    __syncthreads();
#pragma unroll
    for (int j = 0; j < 4; j++)
        Wt[(size_t)(x0 + ty + 8 * j) * Ec + y0 + tx] = f2bf(t[tx][ty + 8 * j]);
}

// ---------------------------------------------------------------------------
// Kernel 1: fused QKV projection via bf16 MFMA.  128x128 tile, BK=64, 4 waves.
// 2-phase double-buffered pipeline with COUNTED vmcnt (T3/T4):
//   prologue: STAGE(0,buf0), STAGE(1,buf1)
//   step t:   vmcnt(8) [oldest stage done] -> barrier -> ds_read all frags
//             -> lgkmcnt(0) -> barrier [buffer free] -> STAGE(t+2, cb) -> MFMA
// vmcnt never drains to 0 in the steady loop; each stage has ~2 K-steps of
// latency slack.  8 gload_lds per wave per stage.
// ---------------------------------------------------------------------------
__global__ __launch_bounds__(256) void qkv_mfma_kernel(
    const ushort_t* __restrict__ xb, const ushort_t* __restrict__ Wt,
    const float* __restrict__ bq, const float* __restrict__ bk,
    const float* __restrict__ bv, ushort_t* __restrict__ qkv)
{
    __shared__ __align__(16) ushort_t As[2][128 * 64];
    __shared__ __align__(16) ushort_t Bs[2][128 * 64];

    const int tid = threadIdx.x;
    const int lane = tid & 63;
    const int wid = tid >> 6;
    const int wr = wid >> 1, wc = wid & 1;
    const int m0 = blockIdx.x * 128;
    const int n0 = blockIdx.y * 128;
    const int which = n0 / Ec;
    const int nm0 = n0 - which * Ec;
    const ushort_t* Wmat = Wt + (size_t)which * Ec * Ec;
    const float* bias = (which == 0) ? bq : (which == 1) ? bk : bv;

    f32x4 acc[4][4];
#pragma unroll
    for (int i = 0; i < 4; i++)
#pragma unroll
        for (int j = 0; j < 4; j++) acc[i][j] = (f32x4){0.f, 0.f, 0.f, 0.f};

    // per-wave staging: 4 chunk-pairs (A,B), source pre-swizzled (rule 21)
#define QKV_STAGE(KT, BUF)                                                       \
    {                                                                            \
        _Pragma("unroll")                                                        \
        for (int c = 0; c < 4; c++) {                                            \
            int ci  = (wid * 4 + c) * 64 + lane;                                 \
            int row = ci >> 3, kc = ci & 7;                                      \
            int kcs = kc ^ (row & 7);                                            \
            int rowA = m0 + row; rowA = rowA < MT ? rowA : MT - 1;               \
            GLOAD_LDS16(xb + (size_t)rowA * Ec + (KT) + kcs * 8,                 \
                        As[BUF] + (size_t)(wid * 4 + c) * 512);                  \
            GLOAD_LDS16(Wmat + (size_t)(nm0 + row) * Ec + (KT) + kcs * 8,        \
                        Bs[BUF] + (size_t)(wid * 4 + c) * 512);                  \
        }                                                                        \
    }

    QKV_STAGE(0, 0);
    QKV_STAGE(64, 1);

    for (int t = 0; t < 6; ++t) {
        const int cb = t & 1;
        if (t < 5) { asm volatile("s_waitcnt vmcnt(8)" ::: "memory"); }
        else       { asm volatile("s_waitcnt vmcnt(0)" ::: "memory"); }
        __builtin_amdgcn_sched_barrier(0);
        __builtin_amdgcn_s_barrier();            // buffer cb staged (all waves)

        short8 a[2][4], b[2][4];
#pragma unroll
        for (int ki = 0; ki < 2; ki++) {
            const int kchunk = ki * 4 + (lane >> 4);
#pragma unroll
            for (int mi = 0; mi < 4; mi++) {
                int row = wr * 64 + mi * 16 + (lane & 15);
                a[ki][mi] = *(const short8*)(As[cb] + row * 64 + ((kchunk ^ (row & 7)) * 8));
            }
#pragma unroll
            for (int ni = 0; ni < 4; ni++) {
                int row = wc * 64 + ni * 16 + (lane & 15);
                b[ki][ni] = *(const short8*)(Bs[cb] + row * 64 + ((kchunk ^ (row & 7)) * 8));
            }
        }
        asm volatile("s_waitcnt lgkmcnt(0)" ::: "memory");
        __builtin_amdgcn_sched_barrier(0);
        __builtin_amdgcn_s_barrier();            // all waves done reading cb

        if (t + 2 < 6) QKV_STAGE((t + 2) * 64, cb);   // refill freed buffer

#pragma unroll
        for (int ki = 0; ki < 2; ki++)
#pragma unroll
            for (int mi = 0; mi < 4; mi++)
#pragma unroll
                for (int ni = 0; ni < 4; ni++)
                    acc[mi][ni] = __builtin_amdgcn_mfma_f32_16x16x32_bf16(
                        a[ki][mi], b[ki][ni], acc[mi][ni], 0, 0, 0);
    }
#undef QKV_STAGE

    const int colL = lane & 15;
    const int rowL = (lane >> 4) * 4;
#pragma unroll
    for (int ni = 0; ni < 4; ni++) {
        int nm = nm0 + wc * 64 + ni * 16 + colL;
        float bv_ = bias[nm];
        int h = nm >> 6, d = nm & 63;
#pragma unroll
        for (int mi = 0; mi < 4; mi++) {
#pragma unroll
            for (int r = 0; r < 4; r++) {
                int m = m0 + wr * 64 + mi * 16 + rowL + r;
                if (m < MT) {
                    int b_ = m / Lc, l = m - b_ * Lc;
                    qkv[(size_t)which * BHLD +
                        ((size_t)(b_ * Hc + h) * Lc + l) * Dc + d] =
                        f2bf(acc[mi][ni][r] + bv_);
                }
            }
        }
    }
}

// ---------------------------------------------------------------------------
// Kernel 2: CLS split-K partials. grid (48, NCH).
// ---------------------------------------------------------------------------
__global__ __launch_bounds__(256) void cls_part_kernel(
    const ushort_t* __restrict__ qkv, float* __restrict__ part)
{
    const int bh = blockIdx.x, ch = blockIdx.y;
    const int base = ch * 256;
    const int count = min(256, Lc - base);
    const ushort_t* Q = qkv + (size_t)bh * Lc * Dc;
    const ushort_t* K = Q + (size_t)BHLD;
    const ushort_t* V = Q + 2 * (size_t)BHLD;

    __shared__ float qs[64];
    __shared__ float ps[256];
    __shared__ float red[256];

    const int tid = threadIdx.x;
    if (tid < 64) qs[tid] = bf2f(Q[tid]);
    __syncthreads();

    float s = -1e30f;
    if (tid < count) {
        const ushort4* kp = (const ushort4*)(K + (size_t)(base + tid) * Dc);
        float acc = 0.f;
#pragma unroll
        for (int c = 0; c < 16; c++) {
            ushort4 kv = kp[c];
            acc += qs[c * 4 + 0] * bf2f(kv.x) + qs[c * 4 + 1] * bf2f(kv.y) +
                   qs[c * 4 + 2] * bf2f(kv.z) + qs[c * 4 + 3] * bf2f(kv.w);
        }
        s = acc * SCALE;
    }
    red[tid] = s; __syncthreads();
    for (int off = 128; off > 0; off >>= 1) {
        if (tid < off) red[tid] = fmaxf(red[tid], red[tid + off]);
        __syncthreads();
    }
    const float m = red[0];
    __syncthreads();

    float p = (tid < count) ? __expf(s - m) : 0.f;
    ps[tid] = p;
    red[tid] = p; __syncthreads();
    for (int off = 128; off > 0; off >>= 1) {
        if (tid < off) red[tid] += red[tid + off];
        __syncthreads();
    }
    const float S = red[0];
    __syncthreads();

    const int d = tid & 63, sl = tid >> 6;
    float acc = 0.f;
    for (int i = sl; i < count; i += 4)
        acc += ps[i] * bf2f(V[(size_t)(base + i) * Dc + d]);
    red[tid] = acc; __syncthreads();
    if (tid < 64) {
        float o = red[tid] + red[tid + 64] + red[tid + 128] + red[tid + 192];
        float* pp = part + (size_t)(bh * NCH + ch) * 66;
        pp[2 + tid] = o;
        if (tid == 0) { pp[0] = m; pp[1] = S; }
    }
}

// ---------------------------------------------------------------------------
// Kernel 3: windowed MFMA attention (NT=7 j-tiles, in-kernel V transpose)
//           + CLS combine.  grid (17, 48), 256 threads (4 waves).
// ---------------------------------------------------------------------------
__global__ __launch_bounds__(256) void win_attn_kernel(
    const ushort_t* __restrict__ qkv, const float* __restrict__ part,
    ushort_t* __restrict__ attnb)
{
    __shared__ __align__(16) ushort_t Kb[128 * 64];   // K rows 0..111 used
    __shared__ __align__(16) ushort_t Vb[64 * 128];   // V^T, chunk-xor (d&15)
    __shared__ __align__(16) ushort_t QP[64 * 128];   // Q (8KB) then P (16KB)

    const int bh = blockIdx.y;
    const int tid = threadIdx.x, lane = tid & 63, wid = tid >> 6;
    const int b_ = bh / Hc, h = bh - b_ * Hc;

    if (blockIdx.x == 16) {
        // -------- CLS combine --------
        if (tid >= 64) return;
        float M = -1e30f;
#pragma unroll
        for (int ch = 0; ch < NCH; ch++)
            M = fmaxf(M, part[(size_t)(bh * NCH + ch) * 66]);
        float S = 0.f, O = 0.f;
#pragma unroll
        for (int ch = 0; ch < NCH; ch++) {
            const float* pp = part + (size_t)(bh * NCH + ch) * 66;
            float w = __expf(pp[0] - M);
            S += pp[1] * w;
            O += pp[2 + tid] * w;
        }
        attnb[(size_t)(b_ * Lc) * Ec + h * 64 + tid] = f2bf(O / S);
        return;
    }

    // -------- windowed branch --------
    const int t = blockIdx.x;
    const int l0 = 1 + t * 64;
    const int k0n = l0 - 16;            // slot j -> kpos k0n + j (j <= 95)
    const ushort_t* Qg = qkv + (size_t)bh * Lc * Dc;
    const ushort_t* Kg = Qg + (size_t)BHLD;
    const ushort_t* Vg = Qg + 2 * (size_t)BHLD;

    // V: global -> regs (112 rows x 8 d-chunks of 16B = 896 chunks)
    short8 vreg[4];
    int vrow[4], vdc[4];
#pragma unroll
    for (int i = 0; i < 4; i++) {
        int ci = i * 256 + tid;
        if (ci < 896) {
            int j = ci >> 3, dc = ci & 7;
            int kp = (j <= 95) ? min(max(k0n + j, 0), 1024) : 0;
            vreg[i] = *(const short8*)(Vg + (size_t)kp * Dc + dc * 8);
            vrow[i] = j; vdc[i] = dc;
        } else { vrow[i] = -1; vdc[i] = 0; }
    }

    // K rows 0..111 (14 wave-chunks) + Q rows 0..63 via global_load_lds
#pragma unroll
    for (int i = 0; i < 4; i++) {
        int wchunk = i * 4 + wid;        // 0..15; K needs 0..13 (uniform/wave)
        if (wchunk < 14) {
            int p = wchunk * 64 + lane;
            int j = p >> 3, c = p & 7, g = c ^ (j & 7);
            int kp = (j <= 95) ? min(max(k0n + j, 0), 1024) : 0;
            GLOAD_LDS16(Kg + (size_t)kp * Dc + g * 8,
                        Kb + (size_t)wchunk * 512);
        }
    }
#pragma unroll
    for (int i = 0; i < 2; i++) {
        int p = (i * 4 + wid) * 64 + lane;
        int q = p >> 3, c = p & 7, g = c ^ (q & 7);
        GLOAD_LDS16(Qg + (size_t)(l0 + q) * Dc + g * 8,
                    QP + (size_t)(i * 4 + wid) * 512);
    }

    // V: regs -> transposed LDS (Vb[d][j], chunk-xor (d&15))
#pragma unroll
    for (int i = 0; i < 4; i++) {
        if (vrow[i] >= 0) {
            int j = vrow[i], jc3 = j >> 3, j7 = j & 7;
#pragma unroll
            for (int z = 0; z < 8; z++) {
                int d = vdc[i] * 8 + z;
                Vb[d * 128 + ((jc3 ^ (d & 15)) * 8) + j7] = (ushort_t)vreg[i][z];
            }
        }
    }
    // zero logical chunks 14,15 of every Vb row (slots 112..127)
    if (tid < 128) {
        int d = tid >> 1, lcn = 14 + (tid & 1);
        *(short8*)(Vb + d * 128 + ((lcn ^ (d & 15)) * 8)) =
            (short8){0, 0, 0, 0, 0, 0, 0, 0};
    }
    __syncthreads();

    // ---- QK^T: wave owns q-tile wid (16 rows) x 7 j-tiles ----
    f32x4 sacc[7];
#pragma unroll
    for (int tj = 0; tj < 7; tj++) sacc[tj] = (f32x4){0.f, 0.f, 0.f, 0.f};
#pragma unroll
    for (int ki = 0; ki < 2; ki++) {
        const int gc = ki * 4 + (lane >> 4);
        const int qrow = wid * 16 + (lane & 15);
        short8 a = *(const short8*)(QP + qrow * 64 + ((gc ^ (qrow & 7)) * 8));
#pragma unroll
        for (int tj = 0; tj < 7; tj++) {
            int jrow = tj * 16 + (lane & 15);
            short8 b = *(const short8*)(Kb + jrow * 64 + ((gc ^ (jrow & 7)) * 8));
            sacc[tj] = __builtin_amdgcn_mfma_f32_16x16x32_bf16(a, b, sacc[tj], 0, 0, 0);
        }
    }
    __syncthreads();   // Q region dead; P may overwrite it

    // ---- softmax (rows q = wid*16 + (lane>>4)*4 + r), write P to LDS ----
    const int qb = wid * 16 + (lane >> 4) * 4;
    const int cl = lane & 15;
    float inv[4];
#pragma unroll
    for (int r = 0; r < 4; r++) {
        const int q = qb + r;
        float sv[7];
        float mx = -1e30f;
#pragma unroll
        for (int tj = 0; tj < 7; tj++) {
            int j = tj * 16 + cl;
            int kp = k0n + j;
            bool valid = (j == 96) ||
                         ((j >= q) && (j <= q + 32) && (kp >= 1) && (kp <= 1024));
            float s = valid ? sacc[tj][r] * SCALE : -1e30f;
            sv[tj] = s;
            mx = fmaxf(mx, s);
        }
        mx = fmaxf(mx, __shfl_xor(mx, 1));
        mx = fmaxf(mx, __shfl_xor(mx, 2));
        mx = fmaxf(mx, __shfl_xor(mx, 4));
        mx = fmaxf(mx, __shfl_xor(mx, 8));
        float sum = 0.f;
#pragma unroll
        for (int tj = 0; tj < 7; tj++) {
            float pv = __expf(sv[tj] - mx);
            sv[tj] = pv;
            sum += pv;
        }
        sum += __shfl_xor(sum, 1);
        sum += __shfl_xor(sum, 2);
        sum += __shfl_xor(sum, 4);
        sum += __shfl_xor(sum, 8);
        inv[r] = 1.f / sum;
#pragma unroll
        for (int tj = 0; tj < 7; tj++) {
            int j = tj * 16 + cl;
            QP[q * 128 + (((j >> 3) ^ (q & 15)) * 8) + (j & 7)] = f2bf(sv[tj]);
        }
    }
    // zero P logical chunks 14,15 (slots 112..127) for this thread's rows
    if (cl == 0) {
#pragma unroll
        for (int r = 0; r < 4; r++) {
            int q = qb + r;
            *(short8*)(QP + q * 128 + ((14 ^ (q & 15)) * 8)) =
                (short8){0, 0, 0, 0, 0, 0, 0, 0};
            *(short8*)(QP + q * 128 + ((15 ^ (q & 15)) * 8)) =
                (short8){0, 0, 0, 0, 0, 0, 0, 0};
        }
    }
    __syncthreads();

    // ---- PV: O(16x64) per wave = 4 k-steps x 4 d-tiles ----
    f32x4 oacc[4];
#pragma unroll
    for (int dt = 0; dt < 4; dt++) oacc[dt] = (f32x4){0.f, 0.f, 0.f, 0.f};
#pragma unroll
    for (int kc = 0; kc < 4; kc++) {
        const int gc = kc * 4 + (lane >> 4);
        const int qrow = wid * 16 + (lane & 15);
        short8 pa = *(const short8*)(QP + qrow * 128 + ((gc ^ (qrow & 15)) * 8));
#pragma unroll
        for (int dt = 0; dt < 4; dt++) {
            int drow = dt * 16 + (lane & 15);
            short8 vb = *(const short8*)(Vb + drow * 128 + ((gc ^ (drow & 15)) * 8));
            oacc[dt] = __builtin_amdgcn_mfma_f32_16x16x32_bf16(pa, vb, oacc[dt], 0, 0, 0);
        }
    }

    // ---- epilogue ----
#pragma unroll
    for (int dt = 0; dt < 4; dt++) {
        int d = dt * 16 + cl;
#pragma unroll
        for (int r = 0; r < 4; r++) {
            int l = l0 + qb + r;
            attnb[(size_t)(b_ * Lc + l) * Ec + h * 64 + d] = f2bf(oacc[dt][r] * inv[r]);
        }
    }
}

// ---------------------------------------------------------------------------
// Kernel 4: output projection via bf16 MFMA, 64x128 tile (grid 129 x 3).
// Same 2-phase counted-vmcnt pipeline as qkv (6 gload_lds per wave per stage).
// ---------------------------------------------------------------------------
__global__ __launch_bounds__(256) void out_mfma_kernel(
    const ushort_t* __restrict__ attn_rows, const ushort_t* __restrict__ Wot,
    const float* __restrict__ bo, float* __restrict__ out)
{
    __shared__ __align__(16) ushort_t As[2][64 * 64];
    __shared__ __align__(16) ushort_t Bs[2][128 * 64];

    const int tid = threadIdx.x;
    const int lane = tid & 63;
    const int wid = tid >> 6;
    const int wr = wid & 1, wc = wid >> 1;
    const int m0 = blockIdx.x * 64;
    const int n0 = blockIdx.y * 128;

    f32x4 acc[2][4];
#pragma unroll
    for (int i = 0; i < 2; i++)
#pragma unroll
        for (int j = 0; j < 4; j++) acc[i][j] = (f32x4){0.f, 0.f, 0.f, 0.f};

#define OUT_STAGE(KT, BUF)                                                       \
    {                                                                            \
        _Pragma("unroll")                                                        \
        for (int c = 0; c < 2; c++) {                                            \
            int ci  = (wid * 2 + c) * 64 + lane;                                 \
            int row = ci >> 3, kc = ci & 7;                                      \
            int kcs = kc ^ (row & 7);                                            \
            int rowA = m0 + row; rowA = rowA < MT ? rowA : MT - 1;               \
            GLOAD_LDS16(attn_rows + (size_t)rowA * Ec + (KT) + kcs * 8,          \
                        As[BUF] + (size_t)(wid * 2 + c) * 512);                  \
        }                                                                        \
        _Pragma("unroll")                                                        \
        for (int c = 0; c < 4; c++) {                                            \
            int ci  = (wid * 4 + c) * 64 + lane;                                 \
            int row = ci >> 3, kc = ci & 7;                                      \
            int kcs = kc ^ (row & 7);                                            \
            GLOAD_LDS16(Wot + (size_t)(n0 + row) * Ec + (KT) + kcs * 8,          \
                        Bs[BUF] + (size_t)(wid * 4 + c) * 512);                  \
        }                                                                        \
    }

    OUT_STAGE(0, 0);
    OUT_STAGE(64, 1);

    for (int t = 0; t < 6; ++t) {
        const int cb = t & 1;
        if (t < 5) { asm volatile("s_waitcnt vmcnt(6)" ::: "memory"); }
        else       { asm volatile("s_waitcnt vmcnt(0)" ::: "memory"); }
        __builtin_amdgcn_sched_barrier(0);
        __builtin_amdgcn_s_barrier();

        short8 a[2][2], b[2][4];
#pragma unroll
        for (int ki = 0; ki < 2; ki++) {
            const int kchunk = ki * 4 + (lane >> 4);
#pragma unroll
            for (int mi = 0; mi < 2; mi++) {
                int row = wr * 32 + mi * 16 + (lane & 15);
                a[ki][mi] = *(const short8*)(As[cb] + row * 64 + ((kchunk ^ (row & 7)) * 8));
            }
#pragma unroll
            for (int ni = 0; ni < 4; ni++) {
                int row = wc * 64 + ni * 16 + (lane & 15);
                b[ki][ni] = *(const short8*)(Bs[cb] + row * 64 + ((kchunk ^ (row & 7)) * 8));
            }
        }
        asm volatile("s_waitcnt lgkmcnt(0)" ::: "memory");
        __builtin_amdgcn_sched_barrier(0);
        __builtin_amdgcn_s_barrier();

        if (t + 2 < 6) OUT_STAGE((t + 2) * 64, cb);

#pragma unroll
        for (int ki = 0; ki < 2; ki++)
#pragma unroll
            for (int mi = 0; mi < 2; mi++)
#pragma unroll
                for (int ni = 0; ni < 4; ni++)
                    acc[mi][ni] = __builtin_amdgcn_mfma_f32_16x16x32_bf16(
                        a[ki][mi], b[ki][ni], acc[mi][ni], 0, 0, 0);
    }
#undef OUT_STAGE

    const int colL = lane & 15;
    const int rowL = (lane >> 4) * 4;
#pragma unroll
    for (int ni = 0; ni < 4; ni++) {
        int n = n0 + wc * 64 + ni * 16 + colL;
        float bo_v = bo[n];
#pragma unroll
        for (int mi = 0; mi < 2; mi++) {
#pragma unroll
            for (int r = 0; r < 4; r++) {
                int m = m0 + wr * 32 + mi * 16 + rowL + r;
                if (m < MT) out[(size_t)m * Ec + n] = acc[mi][ni][r] + bo_v;
            }
        }
    }
}

// ---------------------------------------------------------------------------
extern "C" void kernel_launch(void* const* d_in, const int* in_sizes, int n_in,
                              void* d_out, int out_size, void* d_ws, size_t ws_size,
                              hipStream_t stream)
{
    const float* x  = (const float*)d_in[0];
    const float* Wq = (const float*)d_in[1];
    const float* bq = (const float*)d_in[2];
    const float* Wk = (const float*)d_in[3];
    const float* bk = (const float*)d_in[4];
    const float* Wv = (const float*)d_in[5];
    const float* bv = (const float*)d_in[6];
    const float* Wo = (const float*)d_in[7];
    const float* bo = (const float*)d_in[8];
    float* out = (float*)d_out;

    // ws layout (ushort units, all 16B-aligned):
    // xb | Wt(4) | qkv(3) | attnb | clsp(float)  ~= 26 MB
    ushort_t* xb    = (ushort_t*)d_ws;
    ushort_t* Wt    = xb + (size_t)MT * Ec;                  // 3,148,800
    ushort_t* qkvb  = Wt + (size_t)4 * Ec * Ec;              // + 589,824
    ushort_t* attnb = qkvb + (size_t)3 * BHLD;               // + 9,446,400
    float* clsp     = (float*)(attnb + (size_t)MT * Ec);     // + 3,148,800

    prep_kernel<<<3075 + 576, 256, 0, stream>>>(x, xb, Wq, Wk, Wv, Wo, Wt);

    qkv_mfma_kernel<<<dim3((MT + 127) / 128, 9), 256, 0, stream>>>(
        xb, Wt, bq, bk, bv, qkvb);

    cls_part_kernel<<<dim3(Bc * Hc, NCH), 256, 0, stream>>>(qkvb, clsp);

    win_attn_kernel<<<dim3(17, Bc * Hc), 256, 0, stream>>>(qkvb, clsp, attnb);

    out_mfma_kernel<<<dim3((MT + 63) / 64, 3), 256, 0, stream>>>(
        attnb, Wt + (size_t)3 * Ec * Ec, bo, out);
}